// Round 16
// baseline (542.970 us; speedup 1.0000x reference)
//
#include <hip/hip_runtime.h>

typedef __attribute__((ext_vector_type(8))) short short8;
typedef __attribute__((ext_vector_type(4))) float f32x4;
typedef __attribute__((ext_vector_type(4))) unsigned short us4;
typedef __attribute__((ext_vector_type(8))) unsigned short us8;

__device__ __forceinline__ unsigned short f2bf(float f) {
  union { float f; unsigned u; } v; v.f = f;
  unsigned r = v.u + 0x7fffu + ((v.u >> 16) & 1u);
  return (unsigned short)(r >> 16);
}
__device__ __forceinline__ float bf2f(unsigned short b) {
  union { unsigned u; float f; } v; v.u = ((unsigned)b) << 16;
  return v.f;
}
__device__ __forceinline__ float fexp2(float x) {
  float r; asm("v_exp_f32 %0, %1" : "=v"(r) : "v"(x)); return r;
}
__device__ __forceinline__ unsigned cvtpk(float lo, float hi) {
  unsigned r;
  asm("v_cvt_pk_bf16_f32 %0, %1, %2" : "=v"(r) : "v"(lo), "v"(hi));
  return r;
}
__device__ __forceinline__ float max3f(float a, float b, float c) {
  float r;
  asm("v_max3_f32 %0, %1, %2, %3" : "=v"(r) : "v"(a), "v"(b), "v"(c));
  return r;
}
__device__ __forceinline__ us8 cvt8v(f32x4 a, f32x4 b) {
  us8 o;
  o[0] = f2bf(a[0]); o[1] = f2bf(a[1]); o[2] = f2bf(a[2]); o[3] = f2bf(a[3]);
  o[4] = f2bf(b[0]); o[5] = f2bf(b[1]); o[6] = f2bf(b[2]); o[7] = f2bf(b[3]);
  return o;
}

__device__ __forceinline__ void gload_lds16(const void* g, void* l) {
  __builtin_amdgcn_global_load_lds((const __attribute__((address_space(1))) void*)g,
                                   (__attribute__((address_space(3))) void*)l,
                                   16, 0, 0);
}

#define VMW6() asm volatile("s_waitcnt vmcnt(6)" ::: "memory")
#define VMW4() asm volatile("s_waitcnt vmcnt(4)" ::: "memory")
#define VMW0() asm volatile("s_waitcnt vmcnt(0)" ::: "memory")
#define LGKM0() asm volatile("s_waitcnt lgkmcnt(0)" ::: "memory")

// ---- 128B-row (BK=64) staging/frag: LDS(row,g16) = global(row, g16^(row&7))
template<int R>
__device__ __forceinline__ void stage64(const unsigned short* g, int K, int k0,
                                        unsigned short* lds, int tid) {
  const int lane = tid & 63, w = tid >> 6;
  constexpr int RW = R / 4;
  constexpr int NL = RW / 8;
#pragma unroll
  for (int i = 0; i < NL; i++) {
    const int r0 = w * RW + i * 8;
    const int row = r0 + (lane >> 3);
    const int colb = (((lane & 7) ^ (lane >> 3)) << 4);
    gload_lds16((const char*)(g + (size_t)row * K + k0) + colb, lds + r0 * 64);
  }
}
__device__ __forceinline__ short8 lds_frag(const unsigned short* t, int row, int cb) {
  return *(const short8*)((const char*)t + row * 128 + (cb ^ ((row & 7) << 4)));
}

// ---- Paired-row BK=32 layout: 128B LDS row R holds global rows {2R,2R+1}.
template<int GR>
__device__ __forceinline__ void stage32p(const unsigned short* g, int K, int k0,
                                         unsigned short* lds, int tid) {
  const int lane = tid & 63, w = tid >> 6;
  constexpr int LR = GR / 2;
  constexpr int RW = LR / 4;
  constexpr int NL = RW / 8;
#pragma unroll
  for (int i = 0; i < NL; i++) {
    const int R0 = w * RW + i * 8;
    const int R = R0 + (lane >> 3);
    const int gg = (lane & 7) ^ (R & 7);
    const int grow = 2 * R + (gg >> 2);
    const int gcol = (gg & 3) * 8;
    gload_lds16(g + (size_t)grow * K + k0 + gcol, lds + R0 * 64);
  }
}
__device__ __forceinline__ short8 frag32p(const unsigned short* t, int grow, int qo) {
  const int R = grow >> 1;
  const int g16 = (((grow & 1) << 2) + qo) ^ (R & 7);
  return *(const short8*)((const char*)t + R * 128 + (g16 << 4));
}

// ---------------------------------------------------------------------------
// Split-K GEMM: P[z][M=1024][ldo] (fp32) = A[M,K(z-half)] @ B[N,K]^T.
// BM=64, BN=128, BK=64, 3-buffer depth-2, vmcnt(6). Grid (N/128, 16, 2).
// ---------------------------------------------------------------------------
__global__ __launch_bounds__(256) void gemm_split(
    const unsigned short* __restrict__ A,
    const unsigned short* __restrict__ B,
    int K,
    float* __restrict__ P,
    int ldo)
{
  constexpr int BM = 64, BN = 128, BK = 64;
  __shared__ __align__(16) unsigned short sA[3][BM * BK];
  __shared__ __align__(16) unsigned short sB[3][BN * BK];
  const int tid = threadIdx.x;
  const int lane = tid & 63, w = tid >> 6;
  const int wr = w >> 1, wc = w & 1;
  const int ln = lane & 15, qo = lane >> 4;
  const size_t m0 = (size_t)blockIdx.y * BM, n0 = (size_t)blockIdx.x * BN;
  const int koff = blockIdx.z * (K >> 1);
  const unsigned short* Ab = A + m0 * K;
  const unsigned short* Bb = B + n0 * K;

  const f32x4 z4 = {0.f, 0.f, 0.f, 0.f};
  f32x4 acc[2][4];
#pragma unroll
  for (int i = 0; i < 2; i++)
#pragma unroll
    for (int j = 0; j < 4; j++) acc[i][j] = z4;

  const int nt = K / (2 * BK);
  stage64<BM>(Ab, K, koff, sA[0], tid);
  stage64<BN>(Bb, K, koff, sB[0], tid);
  stage64<BM>(Ab, K, koff + BK, sA[1], tid);
  stage64<BN>(Bb, K, koff + BK, sB[1], tid);

  int cur = 0;
  for (int t = 0; t < nt; ++t) {
    if (t == nt - 1) VMW0(); else VMW6();
    __builtin_amdgcn_s_barrier();
    asm volatile("" ::: "memory");
    if (t + 2 < nt) {
      const int nx = (cur == 0) ? 2 : cur - 1;
      stage64<BM>(Ab, K, koff + (t + 2) * BK, sA[nx], tid);
      stage64<BN>(Bb, K, koff + (t + 2) * BK, sB[nx], tid);
    }
    const unsigned short* cA = sA[cur];
    const unsigned short* cB = sB[cur];
#pragma unroll
    for (int ks = 0; ks < 2; ks++) {
      short8 af[2], bfv[4];
#pragma unroll
      for (int mi = 0; mi < 2; mi++)
        af[mi] = lds_frag(cA, wr * 32 + mi * 16 + ln, ks * 64 + qo * 16);
#pragma unroll
      for (int ni = 0; ni < 4; ni++)
        bfv[ni] = lds_frag(cB, wc * 64 + ni * 16 + ln, ks * 64 + qo * 16);
      __builtin_amdgcn_s_setprio(1);
#pragma unroll
      for (int mi = 0; mi < 2; mi++)
#pragma unroll
        for (int ni = 0; ni < 4; ni++)
          acc[mi][ni] = __builtin_amdgcn_mfma_f32_16x16x32_bf16(af[mi], bfv[ni], acc[mi][ni], 0, 0, 0);
      __builtin_amdgcn_s_setprio(0);
    }
    cur = (cur == 2) ? 0 : cur + 1;
  }

  float* Pz = P + (size_t)blockIdx.z * 1024 * (size_t)ldo;
#pragma unroll
  for (int mi = 0; mi < 2; mi++) {
#pragma unroll
    for (int ni = 0; ni < 4; ni++) {
      const size_t row4 = m0 + wr * 32 + mi * 16 + qo * 4;
      const size_t col  = n0 + wc * 64 + ni * 16 + ln;
#pragma unroll
      for (int r = 0; r < 4; r++)
        Pz[(row4 + r) * (size_t)ldo + col] = acc[mi][ni][r];
    }
  }
}

// ---------------------------------------------------------------------------
// Gate/Up GEMM: BM=128, BN=128 (combined interleaved cols), BK=32 paired-row
// layout, 3-buffer depth-2 counted vmcnt(4), 48KB LDS -> 3 blocks/CU.
// Grid 1-D 704, XCD-chunked m-fastest remap. Epilogue silu(g)*u.
// ---------------------------------------------------------------------------
__global__ __launch_bounds__(256) void gemm_gu(
    const unsigned short* __restrict__ A,
    const unsigned short* __restrict__ B,
    unsigned short* __restrict__ outb)
{
  __shared__ __align__(16) unsigned short sA[3][64 * 64];
  __shared__ __align__(16) unsigned short sB[3][64 * 64];
  const int tid = threadIdx.x;
  const int lane = tid & 63, w = tid >> 6;
  const int wr = w >> 1, wc = w & 1;
  const int ln = lane & 15, qo = lane >> 4;
  const int bid = blockIdx.x;                 // 0..703
  const int swz = (bid & 7) * 88 + (bid >> 3);
  const size_t m0 = (size_t)(swz & 7) * 128;  // m fastest
  const size_t n0 = (size_t)(swz >> 3) * 128;
  const unsigned short* Ab = A + m0 * 2048;
  const unsigned short* Bb = B + n0 * 2048;

  const f32x4 z4 = {0.f, 0.f, 0.f, 0.f};
  f32x4 acc[4][4];
#pragma unroll
  for (int i = 0; i < 4; i++)
#pragma unroll
    for (int j = 0; j < 4; j++) acc[i][j] = z4;

  const int nt = 64;  // 2048 / 32
  stage32p<128>(Ab, 2048, 0, sA[0], tid);
  stage32p<128>(Bb, 2048, 0, sB[0], tid);
  stage32p<128>(Ab, 2048, 32, sA[1], tid);
  stage32p<128>(Bb, 2048, 32, sB[1], tid);

  int cur = 0;
  for (int t = 0; t < nt; ++t) {
    if (t == nt - 1) VMW0(); else VMW4();
    __builtin_amdgcn_s_barrier();
    asm volatile("" ::: "memory");
    if (t + 2 < nt) {
      const int nx = (cur == 0) ? 2 : cur - 1;
      stage32p<128>(Ab, 2048, (t + 2) * 32, sA[nx], tid);
      stage32p<128>(Bb, 2048, (t + 2) * 32, sB[nx], tid);
    }
    const unsigned short* cA = sA[cur];
    const unsigned short* cB = sB[cur];
    short8 af[4], bfv[4];
#pragma unroll
    for (int mi = 0; mi < 4; mi++)
      af[mi] = frag32p(cA, wr * 64 + mi * 16 + ln, qo);
#pragma unroll
    for (int ni = 0; ni < 4; ni++)
      bfv[ni] = frag32p(cB, wc * 64 + ni * 16 + ln, qo);
    __builtin_amdgcn_s_setprio(1);
#pragma unroll
    for (int mi = 0; mi < 4; mi++)
#pragma unroll
      for (int ni = 0; ni < 4; ni++)
        acc[mi][ni] = __builtin_amdgcn_mfma_f32_16x16x32_bf16(af[mi], bfv[ni], acc[mi][ni], 0, 0, 0);
    __builtin_amdgcn_s_setprio(0);
    cur = (cur == 2) ? 0 : cur + 1;
  }

  // pairs: gate = acc[mi][2j], up = acc[mi][2j+1]; out col = n0/2 + wc*32 + j*16 + ln
#pragma unroll
  for (int mi = 0; mi < 4; mi++) {
#pragma unroll
    for (int j = 0; j < 2; j++) {
      const size_t row4 = m0 + wr * 64 + mi * 16 + qo * 4;
      const size_t cg = (n0 >> 1) + wc * 32 + j * 16 + ln;
#pragma unroll
      for (int r = 0; r < 4; r++) {
        float g = acc[mi][2 * j][r], u = acc[mi][2 * j + 1][r];
        outb[(row4 + r) * 5632 + cg] = f2bf(g / (1.f + __expf(-g)) * u);
      }
    }
  }
}

// ---------------------------------------------------------------------------
// Dual-B GEMM (K/V): shares A. BM=64, BN=64, BK=64.
// SPLIT=0: out0 bf16 row-major (ld0), out1 bf16 transposed (ld1).
// SPLIT=1: fp32 partials P[z][1024][1024] (K cols 0-511, V cols 512-1023).
// ---------------------------------------------------------------------------
template<int SPLIT>
__global__ __launch_bounds__(256) void gemm_dual(
    const unsigned short* __restrict__ A,
    const unsigned short* __restrict__ B0,
    const unsigned short* __restrict__ B1,
    int K,
    unsigned short* __restrict__ out0,
    unsigned short* __restrict__ out1,
    float* __restrict__ P,
    int ld0, int ld1)
{
  constexpr int BM = 64, BN = 64, BK = 64;
  __shared__ __align__(16) unsigned short sA[3][BM * BK];
  __shared__ __align__(16) unsigned short sB0[3][BN * BK];
  __shared__ __align__(16) unsigned short sB1[3][BN * BK];
  const int tid = threadIdx.x;
  const int lane = tid & 63, w = tid >> 6;
  const int wr = w >> 1, wc = w & 1;
  const int ln = lane & 15, qo = lane >> 4;
  const size_t m0 = (size_t)blockIdx.y * BM, n0 = (size_t)blockIdx.x * BN;
  const int koff = SPLIT ? blockIdx.z * (K >> 1) : 0;
  const unsigned short* Ab = A + m0 * K;
  const unsigned short* B0b = B0 + n0 * K;
  const unsigned short* B1b = B1 + n0 * K;

  const f32x4 z4 = {0.f, 0.f, 0.f, 0.f};
  f32x4 acc0[2][2], acc1[2][2];
#pragma unroll
  for (int i = 0; i < 2; i++)
#pragma unroll
    for (int j = 0; j < 2; j++) { acc0[i][j] = z4; acc1[i][j] = z4; }

  const int nt = SPLIT ? K / (2 * BK) : K / BK;
  stage64<BM>(Ab, K, koff, sA[0], tid);
  stage64<BN>(B0b, K, koff, sB0[0], tid);
  stage64<BN>(B1b, K, koff, sB1[0], tid);
  stage64<BM>(Ab, K, koff + BK, sA[1], tid);
  stage64<BN>(B0b, K, koff + BK, sB0[1], tid);
  stage64<BN>(B1b, K, koff + BK, sB1[1], tid);

  int cur = 0;
  for (int t = 0; t < nt; ++t) {
    if (t == nt - 1) VMW0(); else VMW6();
    __builtin_amdgcn_s_barrier();
    asm volatile("" ::: "memory");
    if (t + 2 < nt) {
      const int nx = (cur == 0) ? 2 : cur - 1;
      stage64<BM>(Ab, K, koff + (t + 2) * BK, sA[nx], tid);
      stage64<BN>(B0b, K, koff + (t + 2) * BK, sB0[nx], tid);
      stage64<BN>(B1b, K, koff + (t + 2) * BK, sB1[nx], tid);
    }
    const unsigned short* cA = sA[cur];
    const unsigned short* cB0 = sB0[cur];
    const unsigned short* cB1 = sB1[cur];
#pragma unroll
    for (int ks = 0; ks < 2; ks++) {
      short8 af[2], b0f[2], b1f[2];
#pragma unroll
      for (int mi = 0; mi < 2; mi++)
        af[mi] = lds_frag(cA, wr * 32 + mi * 16 + ln, ks * 64 + qo * 16);
#pragma unroll
      for (int ni = 0; ni < 2; ni++) {
        b0f[ni] = lds_frag(cB0, wc * 32 + ni * 16 + ln, ks * 64 + qo * 16);
        b1f[ni] = lds_frag(cB1, wc * 32 + ni * 16 + ln, ks * 64 + qo * 16);
      }
      __builtin_amdgcn_s_setprio(1);
#pragma unroll
      for (int mi = 0; mi < 2; mi++)
#pragma unroll
        for (int ni = 0; ni < 2; ni++) {
          acc0[mi][ni] = __builtin_amdgcn_mfma_f32_16x16x32_bf16(af[mi], b0f[ni], acc0[mi][ni], 0, 0, 0);
          acc1[mi][ni] = __builtin_amdgcn_mfma_f32_16x16x32_bf16(af[mi], b1f[ni], acc1[mi][ni], 0, 0, 0);
        }
      __builtin_amdgcn_s_setprio(0);
    }
    cur = (cur == 2) ? 0 : cur + 1;
  }

#pragma unroll
  for (int mi = 0; mi < 2; mi++) {
#pragma unroll
    for (int ni = 0; ni < 2; ni++) {
      const size_t row4 = m0 + wr * 32 + mi * 16 + qo * 4;
      const size_t col  = n0 + wc * 32 + ni * 16 + ln;
      if (SPLIT) {
        float* Pz = P + (size_t)blockIdx.z * 1048576;
#pragma unroll
        for (int r = 0; r < 4; r++) {
          Pz[(row4 + r) * 1024 + col] = acc0[mi][ni][r];
          Pz[(row4 + r) * 1024 + 512 + col] = acc1[mi][ni][r];
        }
      } else {
#pragma unroll
        for (int r = 0; r < 4; r++)
          out0[(row4 + r) * (size_t)ld0 + col] = f2bf(acc0[mi][ni][r]);
        us4 pk;
        pk[0] = f2bf(acc1[mi][ni][0]); pk[1] = f2bf(acc1[mi][ni][1]);
        pk[2] = f2bf(acc1[mi][ni][2]); pk[3] = f2bf(acc1[mi][ni][3]);
        *(us4*)&out1[col * (size_t)ld1 + row4] = pk;
      }
    }
  }
}

// Combine split-KV partials: kB rows (coalesced) + vtB transposed.
__global__ __launch_bounds__(256) void combine_kv(
    const float* __restrict__ P,
    unsigned short* __restrict__ kB,   // pre-offset to row 2048
    unsigned short* __restrict__ vt)   // pre-offset to key 2048
{
  const int j = blockIdx.x * 256 + threadIdx.x;  // 0..524287
  {
    const int row = j >> 9, col = j & 511;
    float v = P[row * 1024 + col] + P[1048576 + row * 1024 + col];
    kB[row * 512 + col] = f2bf(v);
  }
  {
    const int hd = j >> 10, key = j & 1023;
    float v0 = P[key * 1024 + 512 + hd] + P[1048576 + key * 1024 + 512 + hd];
    vt[(size_t)hd * 3072 + key] = f2bf(v0);
  }
}

// ---------------------------------------------------------------------------
// Flash attention, split-KV by 3; Q read from fp32 split partials
// (sum*0.125*log2e fused). Grid (16, 32, 3) = 1536 blocks, 4 waves.
// 2-buffer K/V; P aliased into sK[cur] (dead after QK^T; extra barrier
// separates QK^T reads from P writes). 32KB LDS -> 5 blocks/CU.
// ---------------------------------------------------------------------------
__global__ __launch_bounds__(256) void attn_k(
    const float* __restrict__ Pq,       // [2][1024][2048] fp32 partials
    const unsigned short* __restrict__ Kb,
    const unsigned short* __restrict__ Vt,
    unsigned short* __restrict__ Op,    // [3][1024][2048] bf16 partials
    float* __restrict__ Ml)             // [3][32][1024][2]
{
  __shared__ __align__(16) unsigned short sK[2][64 * 64];
  __shared__ __align__(16) unsigned short sV[2][64 * 64];
  const int tid = threadIdx.x;
  const int lane = tid & 63, w = tid >> 6;
  const int ln = lane & 15, qo = lane >> 4;
  const int head = blockIdx.y, kvh = head >> 2;
  const int half = blockIdx.z;        // 0..2
  const int qw = blockIdx.x * 64 + w * 16;
  const int key0 = half * 1024;       // 16 tiles of 64 keys each

  const float QS = 0.18033688011112042f;  // 2^-3 * log2(e)
  const float* qr = Pq + (size_t)(qw + ln) * 2048 + head * 64;
  short8 qf[2];
#pragma unroll
  for (int kc = 0; kc < 2; kc++) {
    const float* q0 = qr + kc * 32 + qo * 8;
    f32x4 a0 = *(const f32x4*)(q0);
    f32x4 a1 = *(const f32x4*)(q0 + 4);
    f32x4 b0 = *(const f32x4*)(q0 + 2097152);
    f32x4 b1 = *(const f32x4*)(q0 + 2097152 + 4);
    union { short8 s; uint4 u; } t;
    t.u.x = cvtpk((a0[0] + b0[0]) * QS, (a0[1] + b0[1]) * QS);
    t.u.y = cvtpk((a0[2] + b0[2]) * QS, (a0[3] + b0[3]) * QS);
    t.u.z = cvtpk((a1[0] + b1[0]) * QS, (a1[1] + b1[1]) * QS);
    t.u.w = cvtpk((a1[2] + b1[2]) * QS, (a1[3] + b1[3]) * QS);
    qf[kc] = t.s;
  }

  const f32x4 z4 = {0.f, 0.f, 0.f, 0.f};
  f32x4 oacc[4] = {z4, z4, z4, z4};
  float mrun = -1e30f, lrun = 0.f;

  const unsigned short* Kg = Kb + kvh * 64;
  const unsigned short* Vg = Vt + (size_t)(kvh * 64) * 3072;

  stage64<64>(Kg + (size_t)key0 * 512, 512, 0, sK[0], tid);
  stage64<64>(Vg, 3072, key0, sV[0], tid);

  for (int t = 0; t < 16; ++t) {
    const int cur = t & 1;
    VMW0();
    __builtin_amdgcn_s_barrier();
    asm volatile("" ::: "memory");
    if (t + 1 < 16) {
      stage64<64>(Kg + (size_t)(key0 + (t + 1) * 64) * 512, 512, 0, sK[cur ^ 1], tid);
      stage64<64>(Vg, 3072, key0 + (t + 1) * 64, sV[cur ^ 1], tid);
    }

    f32x4 sacc[4] = {z4, z4, z4, z4};
#pragma unroll
    for (int kc = 0; kc < 2; kc++) {
      short8 kf[4];
#pragma unroll
      for (int mi = 0; mi < 4; mi++)
        kf[mi] = lds_frag(sK[cur], mi * 16 + ln, kc * 64 + qo * 16);
      __builtin_amdgcn_s_setprio(1);
#pragma unroll
      for (int mi = 0; mi < 4; mi++)
        sacc[mi] = __builtin_amdgcn_mfma_f32_16x16x32_bf16(kf[mi], qf[kc], sacc[mi], 0, 0, 0);
      __builtin_amdgcn_s_setprio(0);
    }

    // K tile in sK[cur] is dead after QK^T; reuse it for P. Barrier makes
    // sure every wave's QK^T reads (which span all 64 rows) are complete
    // before any wave writes its P rows into the buffer.
    __syncthreads();
    unsigned short* sPc = sK[cur];

    // max over 16 via v_max3 tree
    float m0 = max3f(sacc[0][0], sacc[0][1], sacc[0][2]);
    float m1 = max3f(sacc[0][3], sacc[1][0], sacc[1][1]);
    float m2 = max3f(sacc[1][2], sacc[1][3], sacc[2][0]);
    float m3 = max3f(sacc[2][1], sacc[2][2], sacc[2][3]);
    float m4 = max3f(sacc[3][0], sacc[3][1], sacc[3][2]);
    float tm = fmaxf(max3f(m0, m1, sacc[3][3]), max3f(m2, m3, m4));
    tm = fmaxf(tm, __shfl_xor(tm, 16));
    tm = fmaxf(tm, __shfl_xor(tm, 32));

    if (!__all(tm <= mrun + 11.f)) {
      const float mn = fmaxf(mrun, tm);
      const float al = fexp2(mrun - mn);
      lrun *= al;
      mrun = mn;
#pragma unroll
      for (int r = 0; r < 4; r++) {
        float ar = __shfl(al, qo * 4 + r);
#pragma unroll
        for (int ni = 0; ni < 4; ni++) oacc[ni][r] *= ar;
      }
    }

    float ts = 0.f;
#pragma unroll
    for (int mi = 0; mi < 4; mi++) {
      float p0 = fexp2(sacc[mi][0] - mrun);
      float p1 = fexp2(sacc[mi][1] - mrun);
      float p2 = fexp2(sacc[mi][2] - mrun);
      float p3 = fexp2(sacc[mi][3] - mrun);
      ts += (p0 + p1) + (p2 + p3);
      uint2 pk2;
      pk2.x = cvtpk(p0, p1);
      pk2.y = cvtpk(p2, p3);
      const int row = w * 16 + ln;
      const int g16 = (2 * mi + (qo >> 1)) ^ (ln & 7);
      *(uint2*)((char*)sPc + row * 128 + (g16 << 4) + ((qo & 1) << 3)) = pk2;
    }
    ts += __shfl_xor(ts, 16);
    ts += __shfl_xor(ts, 32);
    lrun += ts;

#pragma unroll
    for (int ks = 0; ks < 2; ks++) {
      short8 pf = lds_frag(sPc, w * 16 + ln, ks * 64 + qo * 16);
      short8 vf[4];
#pragma unroll
      for (int ni = 0; ni < 4; ni++)
        vf[ni] = lds_frag(sV[cur], ni * 16 + ln, ks * 64 + qo * 16);
      __builtin_amdgcn_s_setprio(1);
#pragma unroll
      for (int ni = 0; ni < 4; ni++)
        oacc[ni] = __builtin_amdgcn_mfma_f32_16x16x32_bf16(pf, vf[ni], oacc[ni], 0, 0, 0);
      __builtin_amdgcn_s_setprio(0);
    }
    LGKM0();
  }

  if (qo == 0)
    *(float2*)&Ml[((size_t)(half * 32 + head) * 1024 + qw + ln) * 2] =
        make_float2(mrun, lrun);
#pragma unroll
  for (int r = 0; r < 4; r++)
#pragma unroll
    for (int ni = 0; ni < 4; ni++)
      Op[(size_t)half * 2097152 + (size_t)(qw + qo * 4 + r) * 2048 + head * 64 + ni * 16 + ln] =
          f2bf(oacc[ni][r]);
}

// Combine the three split-KV slices.
__global__ __launch_bounds__(256) void attn_combine(
    const unsigned short* __restrict__ Op,
    const float* __restrict__ Ml,
    unsigned short* __restrict__ O)
{
  const int f = blockIdx.x * 256 + threadIdx.x;
  const int q = f >> 9;
  const int c = (f & 511) * 4;
  const int head = c >> 6;
  const float2 ml0 = *(const float2*)&Ml[((size_t)head * 1024 + q) * 2];
  const float2 ml1 = *(const float2*)&Ml[((size_t)(32 + head) * 1024 + q) * 2];
  const float2 ml2 = *(const float2*)&Ml[((size_t)(64 + head) * 1024 + q) * 2];
  const float m = fmaxf(max3f(ml0.x, ml1.x, ml2.x), -1e30f);
  const float w0 = fexp2(ml0.x - m), w1 = fexp2(ml1.x - m), w2 = fexp2(ml2.x - m);
  const float inv = 1.f / (w0 * ml0.y + w1 * ml1.y + w2 * ml2.y);
  const us4 o0 = *(const us4*)&Op[(size_t)q * 2048 + c];
  const us4 o1 = *(const us4*)&Op[2097152 + (size_t)q * 2048 + c];
  const us4 o2 = *(const us4*)&Op[4194304 + (size_t)q * 2048 + c];
  us4 o;
#pragma unroll
  for (int j = 0; j < 4; j++)
    o[j] = f2bf((w0 * bf2f(o0[j]) + w1 * bf2f(o1[j]) + w2 * bf2f(o2[j])) * inv);
  *(us4*)&O[(size_t)q * 2048 + c] = o;
}

// ---------------------------------------------------------------------------
// RMSNorm variants. Each block = one row of 2048.
// ---------------------------------------------------------------------------
__global__ __launch_bounds__(256) void rmsnorm_k(const float* __restrict__ in,
                                                 const float* __restrict__ w,
                                                 unsigned short* __restrict__ out) {
  const int row = blockIdx.x;
  const int tid = threadIdx.x;
  const float* x = in + (size_t)row * 2048;
  float4 a = ((const float4*)x)[tid * 2];
  float4 b = ((const float4*)x)[tid * 2 + 1];
  float ss = a.x * a.x + a.y * a.y + a.z * a.z + a.w * a.w +
             b.x * b.x + b.y * b.y + b.z * b.z + b.w * b.w;
#pragma unroll
  for (int d = 1; d < 64; d <<= 1) ss += __shfl_xor(ss, d);
  __shared__ float red[4];
  if ((tid & 63) == 0) red[tid >> 6] = ss;
  __syncthreads();
  float sc = rsqrtf((red[0] + red[1] + red[2] + red[3]) * (1.f / 2048.f) + 1e-6f);
  float4 wa = ((const float4*)w)[tid * 2];
  float4 wb = ((const float4*)w)[tid * 2 + 1];
  us4 o1, o2;
  o1[0] = f2bf(a.x * sc * wa.x); o1[1] = f2bf(a.y * sc * wa.y);
  o1[2] = f2bf(a.z * sc * wa.z); o1[3] = f2bf(a.w * sc * wa.w);
  o2[0] = f2bf(b.x * sc * wb.x); o2[1] = f2bf(b.y * sc * wb.y);
  o2[2] = f2bf(b.z * sc * wb.z); o2[3] = f2bf(b.w * sc * wb.w);
  us4* op = (us4*)&out[(size_t)row * 2048 + tid * 8];
  op[0] = o1; op[1] = o2;
}

// ctf += P0+P1 (O-proj residual), then norm -> out (bf16).
__global__ __launch_bounds__(256) void rmsnorm_add_k(
    float* __restrict__ ctf, const float* __restrict__ P,
    const float* __restrict__ w, unsigned short* __restrict__ out) {
  const int row = blockIdx.x;
  const int tid = threadIdx.x;
  const size_t base = (size_t)row * 2048 + tid * 8;
  float t[8];
  float4 c0 = *(const float4*)&ctf[base], c1 = *(const float4*)&ctf[base + 4];
  float4 p0 = *(const float4*)&P[base], p1 = *(const float4*)&P[base + 4];
  float4 q0 = *(const float4*)&P[base + 2097152], q1 = *(const float4*)&P[base + 2097152 + 4];
  t[0] = c0.x + p0.x + q0.x; t[1] = c0.y + p0.y + q0.y;
  t[2] = c0.z + p0.z + q0.z; t[3] = c0.w + p0.w + q0.w;
  t[4] = c1.x + p1.x + q1.x; t[5] = c1.y + p1.y + q1.y;
  t[6] = c1.z + p1.z + q1.z; t[7] = c1.w + p1.w + q1.w;
  *(float4*)&ctf[base] = make_float4(t[0], t[1], t[2], t[3]);
  *(float4*)&ctf[base + 4] = make_float4(t[4], t[5], t[6], t[7]);
  float ss = 0.f;
#pragma unroll
  for (int i = 0; i < 8; i++) ss += t[i] * t[i];
#pragma unroll
  for (int d = 1; d < 64; d <<= 1) ss += __shfl_xor(ss, d);
  __shared__ float red[4];
  if ((tid & 63) == 0) red[tid >> 6] = ss;
  __syncthreads();
  float sc = rsqrtf((red[0] + red[1] + red[2] + red[3]) * (1.f / 2048.f) + 1e-6f);
  us4 o1, o2;
#pragma unroll
  for (int i = 0; i < 4; i++) o1[i] = f2bf(t[i] * sc * w[tid * 8 + i]);
#pragma unroll
  for (int i = 0; i < 4; i++) o2[i] = f2bf(t[4 + i] * sc * w[tid * 8 + 4 + i]);
  us4* op = (us4*)&out[base];
  op[0] = o1; op[1] = o2;
}

// t = P0+P1+y (down-proj + mlp residual); ctf = t; ctb = bf16(t); y <- norm(t)*w.
__global__ __launch_bounds__(256) void rmsnorm_add2_k(
    const float* __restrict__ P, unsigned short* __restrict__ yb,
    float* __restrict__ ctf, unsigned short* __restrict__ ctb,
    const float* __restrict__ w) {
  const int row = blockIdx.x;
  const int tid = threadIdx.x;
  const size_t base = (size_t)row * 2048 + tid * 8;
  float t[8];
  float4 p0 = *(const float4*)&P[base], p1 = *(const float4*)&P[base + 4];
  float4 q0 = *(const float4*)&P[base + 2097152], q1 = *(const float4*)&P[base + 2097152 + 4];
  us4 y0 = *(const us4*)&yb[base], y1 = *(const us4*)&yb[base + 4];
  t[0] = p0.x + q0.x + bf2f(y0[0]); t[1] = p0.y + q0.y + bf2f(y0[1]);
  t[2] = p0.z + q0.z + bf2f(y0[2]); t[3] = p0.w + q0.w + bf2f(y0[3]);
  t[4] = p1.x + q1.x + bf2f(y1[0]); t[5] = p1.y + q1.y + bf2f(y1[1]);
  t[6] = p1.z + q1.z + bf2f(y1[2]); t[7] = p1.w + q1.w + bf2f(y1[3]);
  *(float4*)&ctf[base] = make_float4(t[0], t[1], t[2], t[3]);
  *(float4*)&ctf[base + 4] = make_float4(t[4], t[5], t[6], t[7]);
  us4 cb0, cb1;
#pragma unroll
  for (int i = 0; i < 4; i++) { cb0[i] = f2bf(t[i]); cb1[i] = f2bf(t[4 + i]); }
  *(us4*)&ctb[base] = cb0; *(us4*)&ctb[base + 4] = cb1;
  float ss = 0.f;
#pragma unroll
  for (int i = 0; i < 8; i++) ss += t[i] * t[i];
#pragma unroll
  for (int d = 1; d < 64; d <<= 1) ss += __shfl_xor(ss, d);
  __shared__ float red[4];
  if ((tid & 63) == 0) red[tid >> 6] = ss;
  __syncthreads();
  float sc = rsqrtf((red[0] + red[1] + red[2] + red[3]) * (1.f / 2048.f) + 1e-6f);
  us4 o1, o2;
#pragma unroll
  for (int i = 0; i < 4; i++) o1[i] = f2bf(t[i] * sc * w[tid * 8 + i]);
#pragma unroll
  for (int i = 0; i < 4; i++) o2[i] = f2bf(t[4 + i] * sc * w[tid * 8 + 4 + i]);
  us4* op = (us4*)&yb[base];
  op[0] = o1; op[1] = o2;
}

// Final: out = P0+P1+y (fp32).
__global__ __launch_bounds__(256) void combine2_k(
    const float* __restrict__ P, const unsigned short* __restrict__ yb,
    float* __restrict__ out) {
  const int j = blockIdx.x * 256 + threadIdx.x;  // float4 idx, 524288
  float4 p0 = ((const float4*)P)[j];
  float4 p1 = ((const float4*)P)[j + 524288];
  us4 y = ((const us4*)yb)[j];
  float4 o;
  o.x = p0.x + p1.x + bf2f(y[0]); o.y = p0.y + p1.y + bf2f(y[1]);
  o.z = p0.z + p1.z + bf2f(y[2]); o.w = p0.w + p1.w + bf2f(y[3]);
  ((float4*)out)[j] = o;
}

// ---------------------------------------------------------------------------
// Segment-major conversion of all fp32 inputs to bf16 (+ ct init fused).
// ---------------------------------------------------------------------------
__global__ __launch_bounds__(256) void cvt_all(
    const float* __restrict__ hid, const float* __restrict__ qw,
    const float* __restrict__ kw, const float* __restrict__ vw,
    const float* __restrict__ ow, const float* __restrict__ gw,
    const float* __restrict__ uw, const float* __restrict__ dw,
    unsigned short* __restrict__ hb, unsigned short* __restrict__ qwB,
    unsigned short* __restrict__ kwB, unsigned short* __restrict__ vwB,
    unsigned short* __restrict__ owB, unsigned short* __restrict__ guB,
    unsigned short* __restrict__ dwB,
    float* __restrict__ ctf, unsigned short* __restrict__ ctb)
{
  const int gid = blockIdx.x * 256 + threadIdx.x;
  const int gs = gridDim.x * 256;
  for (int i = gid; i < 524288; i += gs) {   // hidden 2048x2048
    f32x4 a = __builtin_nontemporal_load(&((const f32x4*)hid)[2 * i]);
    f32x4 b = __builtin_nontemporal_load(&((const f32x4*)hid)[2 * i + 1]);
    us8 o = cvt8v(a, b);
    ((us8*)hb)[i] = o;
    if (i >= 262144) {
      ((f32x4*)ctf)[2 * (i - 262144)] = a;
      ((f32x4*)ctf)[2 * (i - 262144) + 1] = b;
      ((us8*)ctb)[i - 262144] = o;
    }
  }
  for (int i = gid; i < 524288; i += gs) {   // q_w 2048x2048
    f32x4 a = __builtin_nontemporal_load(&((const f32x4*)qw)[2 * i]);
    f32x4 b = __builtin_nontemporal_load(&((const f32x4*)qw)[2 * i + 1]);
    ((us8*)qwB)[i] = cvt8v(a, b);
  }
  for (int i = gid; i < 131072; i += gs) {   // k_w 512x2048
    f32x4 a = __builtin_nontemporal_load(&((const f32x4*)kw)[2 * i]);
    f32x4 b = __builtin_nontemporal_load(&((const f32x4*)kw)[2 * i + 1]);
    ((us8*)kwB)[i] = cvt8v(a, b);
  }
  for (int i = gid; i < 131072; i += gs) {   // v_w 512x2048
    f32x4 a = __builtin_nontemporal_load(&((const f32x4*)vw)[2 * i]);
    f32x4 b = __builtin_nontemporal_load(&((const f32x4*)vw)[2 * i + 1]);
    ((us8*)vwB)[i] = cvt8v(a, b);
  }
  for (int i = gid; i < 524288; i += gs) {   // o_w 2048x2048
    f32x4 a = __builtin_nontemporal_load(&((const f32x4*)ow)[2 * i]);
    f32x4 b = __builtin_nontemporal_load(&((const f32x4*)ow)[2 * i + 1]);
    ((us8*)owB)[i] = cvt8v(a, b);
  }
  for (int i = gid; i < 1441792; i += gs) {  // gate 5632x2048, interleave
    f32x4 a = __builtin_nontemporal_load(&((const f32x4*)gw)[2 * i]);
    f32x4 b = __builtin_nontemporal_load(&((const f32x4*)gw)[2 * i + 1]);
    const int row = i >> 8, c8 = i & 255;
    const int drow = ((row >> 4) << 5) + (row & 15);
    ((us8*)guB)[(drow << 8) + c8] = cvt8v(a, b);
  }
  for (int i = gid; i < 1441792; i += gs) {  // up 5632x2048, interleave+16
    f32x4 a = __builtin_nontemporal_load(&((const f32x4*)uw)[2 * i]);
    f32x4 b = __builtin_nontemporal_load(&((const f32x4*)uw)[2 * i + 1]);
    const int row = i >> 8, c8 = i & 255;
    const int drow = ((row >> 4) << 5) + (row & 15) + 16;
    ((us8*)guB)[(drow << 8) + c8] = cvt8v(a, b);
  }
  for (int i = gid; i < 1441792; i += gs) {  // down 2048x5632
    f32x4 a = __builtin_nontemporal_load(&((const f32x4*)dw)[2 * i]);
    f32x4 b = __builtin_nontemporal_load(&((const f32x4*)dw)[2 * i + 1]);
    ((us8*)dwB)[i] = cvt8v(a, b);
  }
}

// ---------------------------------------------------------------------------
extern "C" void kernel_launch(void* const* d_in, const int* in_sizes, int n_in,
                              void* d_out, int out_size, void* d_ws, size_t ws_size,
                              hipStream_t stream) {
  (void)in_sizes; (void)n_in; (void)out_size; (void)ws_size;
  const float* hidden = (const float*)d_in[0];
  const float* q_w  = (const float*)d_in[1];
  const float* k_w  = (const float*)d_in[2];
  const float* v_w  = (const float*)d_in[3];
  const float* o_w  = (const float*)d_in[4];
  const float* a_nw = (const float*)d_in[5];
  const float* m_nw = (const float*)d_in[6];
  const float* g_w  = (const float*)d_in[7];
  const float* u_w  = (const float*)d_in[8];
  const float* dn_w = (const float*)d_in[9];
  float* out = (float*)d_out;

  char* p = (char*)d_ws;
  size_t off = 0;
  auto take = [&](size_t bytes) -> char* {
    char* r = p + off;
    off += (bytes + 255) & ~(size_t)255;
    return r;
  };
  float* ctf          = (float*)take((size_t)1024 * 2048 * 4);
  unsigned short* ctb = (unsigned short*)take((size_t)1024 * 2048 * 2);
  unsigned short* xb  = (unsigned short*)take((size_t)1024 * 2048 * 2);
  unsigned short* hb  = (unsigned short*)take((size_t)2048 * 2048 * 2);
  unsigned short* qwB = (unsigned short*)take((size_t)2048 * 2048 * 2);
  unsigned short* kwB = (unsigned short*)take((size_t)512 * 2048 * 2);
  unsigned short* vwB = (unsigned short*)take((size_t)512 * 2048 * 2);
  unsigned short* owB = (unsigned short*)take((size_t)2048 * 2048 * 2);
  unsigned short* guB = (unsigned short*)take((size_t)11264 * 2048 * 2);
  unsigned short* dwB = (unsigned short*)take((size_t)2048 * 5632 * 2);
  unsigned short* kB  = (unsigned short*)take((size_t)3072 * 512 * 2);
  unsigned short* vtB = (unsigned short*)take((size_t)512 * 3072 * 2);
  unsigned short* oB  = (unsigned short*)take((size_t)1024 * 2048 * 2);
  unsigned short* gtB = (unsigned short*)take((size_t)1024 * 5632 * 2);
  float* Pd           = (float*)take((size_t)2 * 1024 * 2048 * 4);  // split-K partials

  // attn scratch: 3 Op slices (12MB) alias xb(4MB)+hb(8MB) which are
  // contiguous and dead during attention; Ml (768KB) aliases dead gtB.
  unsigned short* Op = xb;
  float* Ml = (float*)gtB;
  float* PKV = (float*)hb;            // KV split partials alias hb (dead when used)

  dim3 blk(256);
  cvt_all<<<dim3(4096), blk, 0, stream>>>(hidden, q_w, k_w, v_w, o_w, g_w, u_w, dn_w,
                                          hb, qwB, kwB, vwB, owB, guB, dwB, ctf, ctb);

  gemm_dual<0><<<dim3(8, 32), blk, 0, stream>>>(hb, kwB, vwB, 2048, kB, vtB, nullptr, 512, 3072);

  for (int it = 0; it < 2; it++) {
    if (it == 0)
      rmsnorm_k<<<dim3(1024), blk, 0, stream>>>(ctf, a_nw, xb);
    else
      rmsnorm_add2_k<<<dim3(1024), blk, 0, stream>>>(Pd, xb, ctf, ctb, a_nw);
    gemm_split<<<dim3(16, 16, 2), blk, 0, stream>>>(xb, qwB, 2048, Pd, 2048);
    gemm_dual<1><<<dim3(8, 16, 2), blk, 0, stream>>>(ctb, kwB, vwB, 2048,
                                                     nullptr, nullptr, PKV, 0, 0);
    combine_kv<<<dim3(2048), blk, 0, stream>>>(PKV, kB + (size_t)2048 * 512, vtB + 2048);
    attn_k<<<dim3(16, 32, 3), blk, 0, stream>>>(Pd, kB, vtB, Op, Ml);
    attn_combine<<<dim3(2048), blk, 0, stream>>>(Op, Ml, oB);
    gemm_split<<<dim3(16, 16, 2), blk, 0, stream>>>(oB, owB, 2048, Pd, 2048);
    rmsnorm_add_k<<<dim3(1024), blk, 0, stream>>>(ctf, Pd, m_nw, xb);
    gemm_gu<<<dim3(704), blk, 0, stream>>>(xb, guB, gtB);
    gemm_split<<<dim3(16, 16, 2), blk, 0, stream>>>(gtB, dwB, 5632, Pd, 2048);
  }
  combine2_k<<<dim3(2048), blk, 0, stream>>>(Pd, xb, out);
}

// Round 17
// 534.770 us; speedup vs baseline: 1.0153x; 1.0153x over previous
//
#include <hip/hip_runtime.h>

typedef __attribute__((ext_vector_type(8))) short short8;
typedef __attribute__((ext_vector_type(4))) float f32x4;
typedef __attribute__((ext_vector_type(4))) unsigned short us4;
typedef __attribute__((ext_vector_type(8))) unsigned short us8;

__device__ __forceinline__ unsigned short f2bf(float f) {
  union { float f; unsigned u; } v; v.f = f;
  unsigned r = v.u + 0x7fffu + ((v.u >> 16) & 1u);
  return (unsigned short)(r >> 16);
}
__device__ __forceinline__ float bf2f(unsigned short b) {
  union { unsigned u; float f; } v; v.u = ((unsigned)b) << 16;
  return v.f;
}
__device__ __forceinline__ float fexp2(float x) {
  float r; asm("v_exp_f32 %0, %1" : "=v"(r) : "v"(x)); return r;
}
__device__ __forceinline__ unsigned cvtpk(float lo, float hi) {
  unsigned r;
  asm("v_cvt_pk_bf16_f32 %0, %1, %2" : "=v"(r) : "v"(lo), "v"(hi));
  return r;
}
__device__ __forceinline__ float max3f(float a, float b, float c) {
  float r;
  asm("v_max3_f32 %0, %1, %2, %3" : "=v"(r) : "v"(a), "v"(b), "v"(c));
  return r;
}
__device__ __forceinline__ us8 cvt8v(f32x4 a, f32x4 b) {
  us8 o;
  o[0] = f2bf(a[0]); o[1] = f2bf(a[1]); o[2] = f2bf(a[2]); o[3] = f2bf(a[3]);
  o[4] = f2bf(b[0]); o[5] = f2bf(b[1]); o[6] = f2bf(b[2]); o[7] = f2bf(b[3]);
  return o;
}

__device__ __forceinline__ void gload_lds16(const void* g, void* l) {
  __builtin_amdgcn_global_load_lds((const __attribute__((address_space(1))) void*)g,
                                   (__attribute__((address_space(3))) void*)l,
                                   16, 0, 0);
}

#define VMW6() asm volatile("s_waitcnt vmcnt(6)" ::: "memory")
#define VMW4() asm volatile("s_waitcnt vmcnt(4)" ::: "memory")
#define VMW0() asm volatile("s_waitcnt vmcnt(0)" ::: "memory")
#define LGKM0() asm volatile("s_waitcnt lgkmcnt(0)" ::: "memory")

// ---- 128B-row (BK=64) staging/frag: LDS(row,g16) = global(row, g16^(row&7))
template<int R>
__device__ __forceinline__ void stage64(const unsigned short* g, int K, int k0,
                                        unsigned short* lds, int tid) {
  const int lane = tid & 63, w = tid >> 6;
  constexpr int RW = R / 4;
  constexpr int NL = RW / 8;
#pragma unroll
  for (int i = 0; i < NL; i++) {
    const int r0 = w * RW + i * 8;
    const int row = r0 + (lane >> 3);
    const int colb = (((lane & 7) ^ (lane >> 3)) << 4);
    gload_lds16((const char*)(g + (size_t)row * K + k0) + colb, lds + r0 * 64);
  }
}
__device__ __forceinline__ short8 lds_frag(const unsigned short* t, int row, int cb) {
  return *(const short8*)((const char*)t + row * 128 + (cb ^ ((row & 7) << 4)));
}

// ---- Paired-row BK=32 layout: 128B LDS row R holds global rows {2R,2R+1}.
template<int GR>
__device__ __forceinline__ void stage32p(const unsigned short* g, int K, int k0,
                                         unsigned short* lds, int tid) {
  const int lane = tid & 63, w = tid >> 6;
  constexpr int LR = GR / 2;
  constexpr int RW = LR / 4;
  constexpr int NL = RW / 8;
#pragma unroll
  for (int i = 0; i < NL; i++) {
    const int R0 = w * RW + i * 8;
    const int R = R0 + (lane >> 3);
    const int gg = (lane & 7) ^ (R & 7);
    const int grow = 2 * R + (gg >> 2);
    const int gcol = (gg & 3) * 8;
    gload_lds16(g + (size_t)grow * K + k0 + gcol, lds + R0 * 64);
  }
}
__device__ __forceinline__ short8 frag32p(const unsigned short* t, int grow, int qo) {
  const int R = grow >> 1;
  const int g16 = (((grow & 1) << 2) + qo) ^ (R & 7);
  return *(const short8*)((const char*)t + R * 128 + (g16 << 4));
}

// ---------------------------------------------------------------------------
// Split-K GEMM: P[z][M=1024][ldo] (fp32) = A[M,K(z-half)] @ B[N,K]^T.
// BM=64, BN=128, BK=64, 3-buffer depth-2, vmcnt(6). Grid (N/128, 16, 2).
// ---------------------------------------------------------------------------
__global__ __launch_bounds__(256) void gemm_split(
    const unsigned short* __restrict__ A,
    const unsigned short* __restrict__ B,
    int K,
    float* __restrict__ P,
    int ldo)
{
  constexpr int BM = 64, BN = 128, BK = 64;
  __shared__ __align__(16) unsigned short sA[3][BM * BK];
  __shared__ __align__(16) unsigned short sB[3][BN * BK];
  const int tid = threadIdx.x;
  const int lane = tid & 63, w = tid >> 6;
  const int wr = w >> 1, wc = w & 1;
  const int ln = lane & 15, qo = lane >> 4;
  const size_t m0 = (size_t)blockIdx.y * BM, n0 = (size_t)blockIdx.x * BN;
  const int koff = blockIdx.z * (K >> 1);
  const unsigned short* Ab = A + m0 * K;
  const unsigned short* Bb = B + n0 * K;

  const f32x4 z4 = {0.f, 0.f, 0.f, 0.f};
  f32x4 acc[2][4];
#pragma unroll
  for (int i = 0; i < 2; i++)
#pragma unroll
    for (int j = 0; j < 4; j++) acc[i][j] = z4;

  const int nt = K / (2 * BK);
  stage64<BM>(Ab, K, koff, sA[0], tid);
  stage64<BN>(Bb, K, koff, sB[0], tid);
  stage64<BM>(Ab, K, koff + BK, sA[1], tid);
  stage64<BN>(Bb, K, koff + BK, sB[1], tid);

  int cur = 0;
  for (int t = 0; t < nt; ++t) {
    if (t == nt - 1) VMW0(); else VMW6();
    __builtin_amdgcn_s_barrier();
    asm volatile("" ::: "memory");
    if (t + 2 < nt) {
      const int nx = (cur == 0) ? 2 : cur - 1;
      stage64<BM>(Ab, K, koff + (t + 2) * BK, sA[nx], tid);
      stage64<BN>(Bb, K, koff + (t + 2) * BK, sB[nx], tid);
    }
    const unsigned short* cA = sA[cur];
    const unsigned short* cB = sB[cur];
#pragma unroll
    for (int ks = 0; ks < 2; ks++) {
      short8 af[2], bfv[4];
#pragma unroll
      for (int mi = 0; mi < 2; mi++)
        af[mi] = lds_frag(cA, wr * 32 + mi * 16 + ln, ks * 64 + qo * 16);
#pragma unroll
      for (int ni = 0; ni < 4; ni++)
        bfv[ni] = lds_frag(cB, wc * 64 + ni * 16 + ln, ks * 64 + qo * 16);
      __builtin_amdgcn_s_setprio(1);
#pragma unroll
      for (int mi = 0; mi < 2; mi++)
#pragma unroll
        for (int ni = 0; ni < 4; ni++)
          acc[mi][ni] = __builtin_amdgcn_mfma_f32_16x16x32_bf16(af[mi], bfv[ni], acc[mi][ni], 0, 0, 0);
      __builtin_amdgcn_s_setprio(0);
    }
    cur = (cur == 2) ? 0 : cur + 1;
  }

  float* Pz = P + (size_t)blockIdx.z * 1024 * (size_t)ldo;
#pragma unroll
  for (int mi = 0; mi < 2; mi++) {
#pragma unroll
    for (int ni = 0; ni < 4; ni++) {
      const size_t row4 = m0 + wr * 32 + mi * 16 + qo * 4;
      const size_t col  = n0 + wc * 64 + ni * 16 + ln;
#pragma unroll
      for (int r = 0; r < 4; r++)
        Pz[(row4 + r) * (size_t)ldo + col] = acc[mi][ni][r];
    }
  }
}

// ---------------------------------------------------------------------------
// Gate/Up GEMM: BM=128, BN=128 (combined interleaved cols), BK=32 paired-row
// layout, 3-buffer depth-2 counted vmcnt(4), 48KB LDS -> 3 blocks/CU.
// Grid 1-D 704, XCD-chunked m-fastest remap. Epilogue silu(g)*u.
// ---------------------------------------------------------------------------
__global__ __launch_bounds__(256) void gemm_gu(
    const unsigned short* __restrict__ A,
    const unsigned short* __restrict__ B,
    unsigned short* __restrict__ outb)
{
  __shared__ __align__(16) unsigned short sA[3][64 * 64];
  __shared__ __align__(16) unsigned short sB[3][64 * 64];
  const int tid = threadIdx.x;
  const int lane = tid & 63, w = tid >> 6;
  const int wr = w >> 1, wc = w & 1;
  const int ln = lane & 15, qo = lane >> 4;
  const int bid = blockIdx.x;                 // 0..703
  const int swz = (bid & 7) * 88 + (bid >> 3);
  const size_t m0 = (size_t)(swz & 7) * 128;  // m fastest
  const size_t n0 = (size_t)(swz >> 3) * 128;
  const unsigned short* Ab = A + m0 * 2048;
  const unsigned short* Bb = B + n0 * 2048;

  const f32x4 z4 = {0.f, 0.f, 0.f, 0.f};
  f32x4 acc[4][4];
#pragma unroll
  for (int i = 0; i < 4; i++)
#pragma unroll
    for (int j = 0; j < 4; j++) acc[i][j] = z4;

  const int nt = 64;  // 2048 / 32
  stage32p<128>(Ab, 2048, 0, sA[0], tid);
  stage32p<128>(Bb, 2048, 0, sB[0], tid);
  stage32p<128>(Ab, 2048, 32, sA[1], tid);
  stage32p<128>(Bb, 2048, 32, sB[1], tid);

  int cur = 0;
  for (int t = 0; t < nt; ++t) {
    if (t == nt - 1) VMW0(); else VMW4();
    __builtin_amdgcn_s_barrier();
    asm volatile("" ::: "memory");
    if (t + 2 < nt) {
      const int nx = (cur == 0) ? 2 : cur - 1;
      stage32p<128>(Ab, 2048, (t + 2) * 32, sA[nx], tid);
      stage32p<128>(Bb, 2048, (t + 2) * 32, sB[nx], tid);
    }
    const unsigned short* cA = sA[cur];
    const unsigned short* cB = sB[cur];
    short8 af[4], bfv[4];
#pragma unroll
    for (int mi = 0; mi < 4; mi++)
      af[mi] = frag32p(cA, wr * 64 + mi * 16 + ln, qo);
#pragma unroll
    for (int ni = 0; ni < 4; ni++)
      bfv[ni] = frag32p(cB, wc * 64 + ni * 16 + ln, qo);
    __builtin_amdgcn_s_setprio(1);
#pragma unroll
    for (int mi = 0; mi < 4; mi++)
#pragma unroll
      for (int ni = 0; ni < 4; ni++)
        acc[mi][ni] = __builtin_amdgcn_mfma_f32_16x16x32_bf16(af[mi], bfv[ni], acc[mi][ni], 0, 0, 0);
    __builtin_amdgcn_s_setprio(0);
    cur = (cur == 2) ? 0 : cur + 1;
  }

  // pairs: gate = acc[mi][2j], up = acc[mi][2j+1]; out col = n0/2 + wc*32 + j*16 + ln
#pragma unroll
  for (int mi = 0; mi < 4; mi++) {
#pragma unroll
    for (int j = 0; j < 2; j++) {
      const size_t row4 = m0 + wr * 64 + mi * 16 + qo * 4;
      const size_t cg = (n0 >> 1) + wc * 32 + j * 16 + ln;
#pragma unroll
      for (int r = 0; r < 4; r++) {
        float g = acc[mi][2 * j][r], u = acc[mi][2 * j + 1][r];
        outb[(row4 + r) * 5632 + cg] = f2bf(g / (1.f + __expf(-g)) * u);
      }
    }
  }
}

// ---------------------------------------------------------------------------
// Dual-B GEMM (K/V): shares A. BM=64, BN=64, BK=64.
// SPLIT=0: out0 bf16 row-major (ld0), out1 bf16 transposed (ld1).
// SPLIT=1: fp32 partials P[z][1024][1024] (K cols 0-511, V cols 512-1023).
// ---------------------------------------------------------------------------
template<int SPLIT>
__global__ __launch_bounds__(256) void gemm_dual(
    const unsigned short* __restrict__ A,
    const unsigned short* __restrict__ B0,
    const unsigned short* __restrict__ B1,
    int K,
    unsigned short* __restrict__ out0,
    unsigned short* __restrict__ out1,
    float* __restrict__ P,
    int ld0, int ld1)
{
  constexpr int BM = 64, BN = 64, BK = 64;
  __shared__ __align__(16) unsigned short sA[3][BM * BK];
  __shared__ __align__(16) unsigned short sB0[3][BN * BK];
  __shared__ __align__(16) unsigned short sB1[3][BN * BK];
  const int tid = threadIdx.x;
  const int lane = tid & 63, w = tid >> 6;
  const int wr = w >> 1, wc = w & 1;
  const int ln = lane & 15, qo = lane >> 4;
  const size_t m0 = (size_t)blockIdx.y * BM, n0 = (size_t)blockIdx.x * BN;
  const int koff = SPLIT ? blockIdx.z * (K >> 1) : 0;
  const unsigned short* Ab = A + m0 * K;
  const unsigned short* B0b = B0 + n0 * K;
  const unsigned short* B1b = B1 + n0 * K;

  const f32x4 z4 = {0.f, 0.f, 0.f, 0.f};
  f32x4 acc0[2][2], acc1[2][2];
#pragma unroll
  for (int i = 0; i < 2; i++)
#pragma unroll
    for (int j = 0; j < 2; j++) { acc0[i][j] = z4; acc1[i][j] = z4; }

  const int nt = SPLIT ? K / (2 * BK) : K / BK;
  stage64<BM>(Ab, K, koff, sA[0], tid);
  stage64<BN>(B0b, K, koff, sB0[0], tid);
  stage64<BN>(B1b, K, koff, sB1[0], tid);
  stage64<BM>(Ab, K, koff + BK, sA[1], tid);
  stage64<BN>(B0b, K, koff + BK, sB0[1], tid);
  stage64<BN>(B1b, K, koff + BK, sB1[1], tid);

  int cur = 0;
  for (int t = 0; t < nt; ++t) {
    if (t == nt - 1) VMW0(); else VMW6();
    __builtin_amdgcn_s_barrier();
    asm volatile("" ::: "memory");
    if (t + 2 < nt) {
      const int nx = (cur == 0) ? 2 : cur - 1;
      stage64<BM>(Ab, K, koff + (t + 2) * BK, sA[nx], tid);
      stage64<BN>(B0b, K, koff + (t + 2) * BK, sB0[nx], tid);
      stage64<BN>(B1b, K, koff + (t + 2) * BK, sB1[nx], tid);
    }
    const unsigned short* cA = sA[cur];
    const unsigned short* cB0 = sB0[cur];
    const unsigned short* cB1 = sB1[cur];
#pragma unroll
    for (int ks = 0; ks < 2; ks++) {
      short8 af[2], b0f[2], b1f[2];
#pragma unroll
      for (int mi = 0; mi < 2; mi++)
        af[mi] = lds_frag(cA, wr * 32 + mi * 16 + ln, ks * 64 + qo * 16);
#pragma unroll
      for (int ni = 0; ni < 2; ni++) {
        b0f[ni] = lds_frag(cB0, wc * 32 + ni * 16 + ln, ks * 64 + qo * 16);
        b1f[ni] = lds_frag(cB1, wc * 32 + ni * 16 + ln, ks * 64 + qo * 16);
      }
      __builtin_amdgcn_s_setprio(1);
#pragma unroll
      for (int mi = 0; mi < 2; mi++)
#pragma unroll
        for (int ni = 0; ni < 2; ni++) {
          acc0[mi][ni] = __builtin_amdgcn_mfma_f32_16x16x32_bf16(af[mi], b0f[ni], acc0[mi][ni], 0, 0, 0);
          acc1[mi][ni] = __builtin_amdgcn_mfma_f32_16x16x32_bf16(af[mi], b1f[ni], acc1[mi][ni], 0, 0, 0);
        }
      __builtin_amdgcn_s_setprio(0);
    }
    cur = (cur == 2) ? 0 : cur + 1;
  }

#pragma unroll
  for (int mi = 0; mi < 2; mi++) {
#pragma unroll
    for (int ni = 0; ni < 2; ni++) {
      const size_t row4 = m0 + wr * 32 + mi * 16 + qo * 4;
      const size_t col  = n0 + wc * 32 + ni * 16 + ln;
      if (SPLIT) {
        float* Pz = P + (size_t)blockIdx.z * 1048576;
#pragma unroll
        for (int r = 0; r < 4; r++) {
          Pz[(row4 + r) * 1024 + col] = acc0[mi][ni][r];
          Pz[(row4 + r) * 1024 + 512 + col] = acc1[mi][ni][r];
        }
      } else {
#pragma unroll
        for (int r = 0; r < 4; r++)
          out0[(row4 + r) * (size_t)ld0 + col] = f2bf(acc0[mi][ni][r]);
        us4 pk;
        pk[0] = f2bf(acc1[mi][ni][0]); pk[1] = f2bf(acc1[mi][ni][1]);
        pk[2] = f2bf(acc1[mi][ni][2]); pk[3] = f2bf(acc1[mi][ni][3]);
        *(us4*)&out1[col * (size_t)ld1 + row4] = pk;
      }
    }
  }
}

// Combine split-KV partials: kB rows (coalesced) + vtB transposed.
__global__ __launch_bounds__(256) void combine_kv(
    const float* __restrict__ P,
    unsigned short* __restrict__ kB,   // pre-offset to row 2048
    unsigned short* __restrict__ vt)   // pre-offset to key 2048
{
  const int j = blockIdx.x * 256 + threadIdx.x;  // 0..524287
  {
    const int row = j >> 9, col = j & 511;
    float v = P[row * 1024 + col] + P[1048576 + row * 1024 + col];
    kB[row * 512 + col] = f2bf(v);
  }
  {
    const int hd = j >> 10, key = j & 1023;
    float v0 = P[key * 1024 + 512 + hd] + P[1048576 + key * 1024 + 512 + hd];
    vt[(size_t)hd * 3072 + key] = f2bf(v0);
  }
}

// ---------------------------------------------------------------------------
// Flash attention, split-KV by 2; Q read from fp32 split partials
// (sum*0.125*log2e fused). Grid (16, 32, 2), 4 waves. 2-buffer K/V
// (40KB LDS -> 4 blocks/CU). P packed via v_cvt_pk_bf16_f32; max via v_max3.
// ---------------------------------------------------------------------------
__global__ __launch_bounds__(256) void attn_k(
    const float* __restrict__ Pq,       // [2][1024][2048] fp32 partials
    const unsigned short* __restrict__ Kb,
    const unsigned short* __restrict__ Vt,
    unsigned short* __restrict__ Op,
    float* __restrict__ Ml)
{
  __shared__ __align__(16) unsigned short sK[2][64 * 64];
  __shared__ __align__(16) unsigned short sV[2][64 * 64];
  __shared__ __align__(16) unsigned short sP[64 * 64];
  const int tid = threadIdx.x;
  const int lane = tid & 63, w = tid >> 6;
  const int ln = lane & 15, qo = lane >> 4;
  const int head = blockIdx.y, kvh = head >> 2;
  const int half = blockIdx.z;
  const int qw = blockIdx.x * 64 + w * 16;
  const int key0 = half * 1536;

  const float QS = 0.18033688011112042f;  // 2^-3 * log2(e)
  const float* qr = Pq + (size_t)(qw + ln) * 2048 + head * 64;
  short8 qf[2];
#pragma unroll
  for (int kc = 0; kc < 2; kc++) {
    const float* q0 = qr + kc * 32 + qo * 8;
    f32x4 a0 = *(const f32x4*)(q0);
    f32x4 a1 = *(const f32x4*)(q0 + 4);
    f32x4 b0 = *(const f32x4*)(q0 + 2097152);
    f32x4 b1 = *(const f32x4*)(q0 + 2097152 + 4);
    union { short8 s; uint4 u; } t;
    t.u.x = cvtpk((a0[0] + b0[0]) * QS, (a0[1] + b0[1]) * QS);
    t.u.y = cvtpk((a0[2] + b0[2]) * QS, (a0[3] + b0[3]) * QS);
    t.u.z = cvtpk((a1[0] + b1[0]) * QS, (a1[1] + b1[1]) * QS);
    t.u.w = cvtpk((a1[2] + b1[2]) * QS, (a1[3] + b1[3]) * QS);
    qf[kc] = t.s;
  }

  const f32x4 z4 = {0.f, 0.f, 0.f, 0.f};
  f32x4 oacc[4] = {z4, z4, z4, z4};
  float mrun = -1e30f, lrun = 0.f;

  const unsigned short* Kg = Kb + kvh * 64;
  const unsigned short* Vg = Vt + (size_t)(kvh * 64) * 3072;

  stage64<64>(Kg + (size_t)key0 * 512, 512, 0, sK[0], tid);
  stage64<64>(Vg, 3072, key0, sV[0], tid);

  for (int t = 0; t < 24; ++t) {
    const int cur = t & 1;
    VMW0();
    __builtin_amdgcn_s_barrier();
    asm volatile("" ::: "memory");
    if (t + 1 < 24) {
      stage64<64>(Kg + (size_t)(key0 + (t + 1) * 64) * 512, 512, 0, sK[cur ^ 1], tid);
      stage64<64>(Vg, 3072, key0 + (t + 1) * 64, sV[cur ^ 1], tid);
    }

    f32x4 sacc[4] = {z4, z4, z4, z4};
#pragma unroll
    for (int kc = 0; kc < 2; kc++) {
      short8 kf[4];
#pragma unroll
      for (int mi = 0; mi < 4; mi++)
        kf[mi] = lds_frag(sK[cur], mi * 16 + ln, kc * 64 + qo * 16);
      __builtin_amdgcn_s_setprio(1);
#pragma unroll
      for (int mi = 0; mi < 4; mi++)
        sacc[mi] = __builtin_amdgcn_mfma_f32_16x16x32_bf16(kf[mi], qf[kc], sacc[mi], 0, 0, 0);
      __builtin_amdgcn_s_setprio(0);
    }

    // max over 16 via v_max3 tree (7 ops)
    float m0 = max3f(sacc[0][0], sacc[0][1], sacc[0][2]);
    float m1 = max3f(sacc[0][3], sacc[1][0], sacc[1][1]);
    float m2 = max3f(sacc[1][2], sacc[1][3], sacc[2][0]);
    float m3 = max3f(sacc[2][1], sacc[2][2], sacc[2][3]);
    float m4 = max3f(sacc[3][0], sacc[3][1], sacc[3][2]);
    float tm = fmaxf(max3f(m0, m1, sacc[3][3]), max3f(m2, m3, m4));
    tm = fmaxf(tm, __shfl_xor(tm, 16));
    tm = fmaxf(tm, __shfl_xor(tm, 32));

    if (!__all(tm <= mrun + 11.f)) {
      const float mn = fmaxf(mrun, tm);
      const float al = fexp2(mrun - mn);
      lrun *= al;
      mrun = mn;
#pragma unroll
      for (int r = 0; r < 4; r++) {
        float ar = __shfl(al, qo * 4 + r);
#pragma unroll
        for (int ni = 0; ni < 4; ni++) oacc[ni][r] *= ar;
      }
    }

    float ts = 0.f;
#pragma unroll
    for (int mi = 0; mi < 4; mi++) {
      float p0 = fexp2(sacc[mi][0] - mrun);
      float p1 = fexp2(sacc[mi][1] - mrun);
      float p2 = fexp2(sacc[mi][2] - mrun);
      float p3 = fexp2(sacc[mi][3] - mrun);
      ts += (p0 + p1) + (p2 + p3);
      uint2 pk2;
      pk2.x = cvtpk(p0, p1);
      pk2.y = cvtpk(p2, p3);
      const int row = w * 16 + ln;
      const int g16 = (2 * mi + (qo >> 1)) ^ (ln & 7);
      *(uint2*)((char*)sP + row * 128 + (g16 << 4) + ((qo & 1) << 3)) = pk2;
    }
    ts += __shfl_xor(ts, 16);
    ts += __shfl_xor(ts, 32);
    lrun += ts;

#pragma unroll
    for (int ks = 0; ks < 2; ks++) {
      short8 pf = lds_frag(sP, w * 16 + ln, ks * 64 + qo * 16);
      short8 vf[4];
#pragma unroll
      for (int ni = 0; ni < 4; ni++)
        vf[ni] = lds_frag(sV[cur], ni * 16 + ln, ks * 64 + qo * 16);
      __builtin_amdgcn_s_setprio(1);
#pragma unroll
      for (int ni = 0; ni < 4; ni++)
        oacc[ni] = __builtin_amdgcn_mfma_f32_16x16x32_bf16(pf, vf[ni], oacc[ni], 0, 0, 0);
      __builtin_amdgcn_s_setprio(0);
    }
    LGKM0();
  }

  if (qo == 0)
    *(float2*)&Ml[((size_t)(half * 32 + head) * 1024 + qw + ln) * 2] =
        make_float2(mrun, lrun);
#pragma unroll
  for (int r = 0; r < 4; r++)
#pragma unroll
    for (int ni = 0; ni < 4; ni++)
      Op[(size_t)half * 2097152 + (size_t)(qw + qo * 4 + r) * 2048 + head * 64 + ni * 16 + ln] =
          f2bf(oacc[ni][r]);
}

__global__ __launch_bounds__(256) void attn_combine(
    const unsigned short* __restrict__ Op,
    const float* __restrict__ Ml,
    unsigned short* __restrict__ O)
{
  const int f = blockIdx.x * 256 + threadIdx.x;
  const int q = f >> 9;
  const int c = (f & 511) * 4;
  const int head = c >> 6;
  const float2 ml0 = *(const float2*)&Ml[((size_t)head * 1024 + q) * 2];
  const float2 ml1 = *(const float2*)&Ml[((size_t)(32 + head) * 1024 + q) * 2];
  const float m = fmaxf(ml0.x, ml1.x);
  const float w0 = fexp2(ml0.x - m), w1 = fexp2(ml1.x - m);
  const float inv = 1.f / (w0 * ml0.y + w1 * ml1.y);
  const us4 o0 = *(const us4*)&Op[(size_t)q * 2048 + c];
  const us4 o1 = *(const us4*)&Op[2097152 + (size_t)q * 2048 + c];
  us4 o;
#pragma unroll
  for (int j = 0; j < 4; j++)
    o[j] = f2bf((w0 * bf2f(o0[j]) + w1 * bf2f(o1[j])) * inv);
  *(us4*)&O[(size_t)q * 2048 + c] = o;
}

// ---------------------------------------------------------------------------
// RMSNorm variants. Each block = one row of 2048.
// ---------------------------------------------------------------------------
__global__ __launch_bounds__(256) void rmsnorm_k(const float* __restrict__ in,
                                                 const float* __restrict__ w,
                                                 unsigned short* __restrict__ out) {
  const int row = blockIdx.x;
  const int tid = threadIdx.x;
  const float* x = in + (size_t)row * 2048;
  float4 a = ((const float4*)x)[tid * 2];
  float4 b = ((const float4*)x)[tid * 2 + 1];
  float ss = a.x * a.x + a.y * a.y + a.z * a.z + a.w * a.w +
             b.x * b.x + b.y * b.y + b.z * b.z + b.w * b.w;
#pragma unroll
  for (int d = 1; d < 64; d <<= 1) ss += __shfl_xor(ss, d);
  __shared__ float red[4];
  if ((tid & 63) == 0) red[tid >> 6] = ss;
  __syncthreads();
  float sc = rsqrtf((red[0] + red[1] + red[2] + red[3]) * (1.f / 2048.f) + 1e-6f);
  float4 wa = ((const float4*)w)[tid * 2];
  float4 wb = ((const float4*)w)[tid * 2 + 1];
  us4 o1, o2;
  o1[0] = f2bf(a.x * sc * wa.x); o1[1] = f2bf(a.y * sc * wa.y);
  o1[2] = f2bf(a.z * sc * wa.z); o1[3] = f2bf(a.w * sc * wa.w);
  o2[0] = f2bf(b.x * sc * wb.x); o2[1] = f2bf(b.y * sc * wb.y);
  o2[2] = f2bf(b.z * sc * wb.z); o2[3] = f2bf(b.w * sc * wb.w);
  us4* op = (us4*)&out[(size_t)row * 2048 + tid * 8];
  op[0] = o1; op[1] = o2;
}

// ctf += P0+P1 (O-proj residual), then norm -> out (bf16).
__global__ __launch_bounds__(256) void rmsnorm_add_k(
    float* __restrict__ ctf, const float* __restrict__ P,
    const float* __restrict__ w, unsigned short* __restrict__ out) {
  const int row = blockIdx.x;
  const int tid = threadIdx.x;
  const size_t base = (size_t)row * 2048 + tid * 8;
  float t[8];
  float4 c0 = *(const float4*)&ctf[base], c1 = *(const float4*)&ctf[base + 4];
  float4 p0 = *(const float4*)&P[base], p1 = *(const float4*)&P[base + 4];
  float4 q0 = *(const float4*)&P[base + 2097152], q1 = *(const float4*)&P[base + 2097152 + 4];
  t[0] = c0.x + p0.x + q0.x; t[1] = c0.y + p0.y + q0.y;
  t[2] = c0.z + p0.z + q0.z; t[3] = c0.w + p0.w + q0.w;
  t[4] = c1.x + p1.x + q1.x; t[5] = c1.y + p1.y + q1.y;
  t[6] = c1.z + p1.z + q1.z; t[7] = c1.w + p1.w + q1.w;
  *(float4*)&ctf[base] = make_float4(t[0], t[1], t[2], t[3]);
  *(float4*)&ctf[base + 4] = make_float4(t[4], t[5], t[6], t[7]);
  float ss = 0.f;
#pragma unroll
  for (int i = 0; i < 8; i++) ss += t[i] * t[i];
#pragma unroll
  for (int d = 1; d < 64; d <<= 1) ss += __shfl_xor(ss, d);
  __shared__ float red[4];
  if ((tid & 63) == 0) red[tid >> 6] = ss;
  __syncthreads();
  float sc = rsqrtf((red[0] + red[1] + red[2] + red[3]) * (1.f / 2048.f) + 1e-6f);
  us4 o1, o2;
#pragma unroll
  for (int i = 0; i < 4; i++) o1[i] = f2bf(t[i] * sc * w[tid * 8 + i]);
#pragma unroll
  for (int i = 0; i < 4; i++) o2[i] = f2bf(t[4 + i] * sc * w[tid * 8 + 4 + i]);
  us4* op = (us4*)&out[base];
  op[0] = o1; op[1] = o2;
}

// t = P0+P1+y (down-proj + mlp residual); ctf = t; ctb = bf16(t); y <- norm(t)*w.
__global__ __launch_bounds__(256) void rmsnorm_add2_k(
    const float* __restrict__ P, unsigned short* __restrict__ yb,
    float* __restrict__ ctf, unsigned short* __restrict__ ctb,
    const float* __restrict__ w) {
  const int row = blockIdx.x;
  const int tid = threadIdx.x;
  const size_t base = (size_t)row * 2048 + tid * 8;
  float t[8];
  float4 p0 = *(const float4*)&P[base], p1 = *(const float4*)&P[base + 4];
  float4 q0 = *(const float4*)&P[base + 2097152], q1 = *(const float4*)&P[base + 2097152 + 4];
  us4 y0 = *(const us4*)&yb[base], y1 = *(const us4*)&yb[base + 4];
  t[0] = p0.x + q0.x + bf2f(y0[0]); t[1] = p0.y + q0.y + bf2f(y0[1]);
  t[2] = p0.z + q0.z + bf2f(y0[2]); t[3] = p0.w + q0.w + bf2f(y0[3]);
  t[4] = p1.x + q1.x + bf2f(y1[0]); t[5] = p1.y + q1.y + bf2f(y1[1]);
  t[6] = p1.z + q1.z + bf2f(y1[2]); t[7] = p1.w + q1.w + bf2f(y1[3]);
  *(float4*)&ctf[base] = make_float4(t[0], t[1], t[2], t[3]);
  *(float4*)&ctf[base + 4] = make_float4(t[4], t[5], t[6], t[7]);
  us4 cb0, cb1;
#pragma unroll
  for (int i = 0; i < 4; i++) { cb0[i] = f2bf(t[i]); cb1[i] = f2bf(t[4 + i]); }
  *(us4*)&ctb[base] = cb0; *(us4*)&ctb[base + 4] = cb1;
  float ss = 0.f;
#pragma unroll
  for (int i = 0; i < 8; i++) ss += t[i] * t[i];
#pragma unroll
  for (int d = 1; d < 64; d <<= 1) ss += __shfl_xor(ss, d);
  __shared__ float red[4];
  if ((tid & 63) == 0) red[tid >> 6] = ss;
  __syncthreads();
  float sc = rsqrtf((red[0] + red[1] + red[2] + red[3]) * (1.f / 2048.f) + 1e-6f);
  us4 o1, o2;
#pragma unroll
  for (int i = 0; i < 4; i++) o1[i] = f2bf(t[i] * sc * w[tid * 8 + i]);
#pragma unroll
  for (int i = 0; i < 4; i++) o2[i] = f2bf(t[4 + i] * sc * w[tid * 8 + 4 + i]);
  us4* op = (us4*)&yb[base];
  op[0] = o1; op[1] = o2;
}

// Final: out = P0+P1+y (fp32).
__global__ __launch_bounds__(256) void combine2_k(
    const float* __restrict__ P, const unsigned short* __restrict__ yb,
    float* __restrict__ out) {
  const int j = blockIdx.x * 256 + threadIdx.x;  // float4 idx, 524288
  float4 p0 = ((const float4*)P)[j];
  float4 p1 = ((const float4*)P)[j + 524288];
  us4 y = ((const us4*)yb)[j];
  float4 o;
  o.x = p0.x + p1.x + bf2f(y[0]); o.y = p0.y + p1.y + bf2f(y[1]);
  o.z = p0.z + p1.z + bf2f(y[2]); o.w = p0.w + p1.w + bf2f(y[3]);
  ((float4*)out)[j] = o;
}

// ---------------------------------------------------------------------------
// Segment-major conversion of all fp32 inputs to bf16 (+ ct init fused).
// ---------------------------------------------------------------------------
__global__ __launch_bounds__(256) void cvt_all(
    const float* __restrict__ hid, const float* __restrict__ qw,
    const float* __restrict__ kw, const float* __restrict__ vw,
    const float* __restrict__ ow, const float* __restrict__ gw,
    const float* __restrict__ uw, const float* __restrict__ dw,
    unsigned short* __restrict__ hb, unsigned short* __restrict__ qwB,
    unsigned short* __restrict__ kwB, unsigned short* __restrict__ vwB,
    unsigned short* __restrict__ owB, unsigned short* __restrict__ guB,
    unsigned short* __restrict__ dwB,
    float* __restrict__ ctf, unsigned short* __restrict__ ctb)
{
  const int gid = blockIdx.x * 256 + threadIdx.x;
  const int gs = gridDim.x * 256;
  for (int i = gid; i < 524288; i += gs) {   // hidden 2048x2048
    f32x4 a = __builtin_nontemporal_load(&((const f32x4*)hid)[2 * i]);
    f32x4 b = __builtin_nontemporal_load(&((const f32x4*)hid)[2 * i + 1]);
    us8 o = cvt8v(a, b);
    ((us8*)hb)[i] = o;
    if (i >= 262144) {
      ((f32x4*)ctf)[2 * (i - 262144)] = a;
      ((f32x4*)ctf)[2 * (i - 262144) + 1] = b;
      ((us8*)ctb)[i - 262144] = o;
    }
  }
  for (int i = gid; i < 524288; i += gs) {   // q_w 2048x2048
    f32x4 a = __builtin_nontemporal_load(&((const f32x4*)qw)[2 * i]);
    f32x4 b = __builtin_nontemporal_load(&((const f32x4*)qw)[2 * i + 1]);
    ((us8*)qwB)[i] = cvt8v(a, b);
  }
  for (int i = gid; i < 131072; i += gs) {   // k_w 512x2048
    f32x4 a = __builtin_nontemporal_load(&((const f32x4*)kw)[2 * i]);
    f32x4 b = __builtin_nontemporal_load(&((const f32x4*)kw)[2 * i + 1]);
    ((us8*)kwB)[i] = cvt8v(a, b);
  }
  for (int i = gid; i < 131072; i += gs) {   // v_w 512x2048
    f32x4 a = __builtin_nontemporal_load(&((const f32x4*)vw)[2 * i]);
    f32x4 b = __builtin_nontemporal_load(&((const f32x4*)vw)[2 * i + 1]);
    ((us8*)vwB)[i] = cvt8v(a, b);
  }
  for (int i = gid; i < 524288; i += gs) {   // o_w 2048x2048
    f32x4 a = __builtin_nontemporal_load(&((const f32x4*)ow)[2 * i]);
    f32x4 b = __builtin_nontemporal_load(&((const f32x4*)ow)[2 * i + 1]);
    ((us8*)owB)[i] = cvt8v(a, b);
  }
  for (int i = gid; i < 1441792; i += gs) {  // gate 5632x2048, interleave
    f32x4 a = __builtin_nontemporal_load(&((const f32x4*)gw)[2 * i]);
    f32x4 b = __builtin_nontemporal_load(&((const f32x4*)gw)[2 * i + 1]);
    const int row = i >> 8, c8 = i & 255;
    const int drow = ((row >> 4) << 5) + (row & 15);
    ((us8*)guB)[(drow << 8) + c8] = cvt8v(a, b);
  }
  for (int i = gid; i < 1441792; i += gs) {  // up 5632x2048, interleave+16
    f32x4 a = __builtin_nontemporal_load(&((const f32x4*)uw)[2 * i]);
    f32x4 b = __builtin_nontemporal_load(&((const f32x4*)uw)[2 * i + 1]);
    const int row = i >> 8, c8 = i & 255;
    const int drow = ((row >> 4) << 5) + (row & 15) + 16;
    ((us8*)guB)[(drow << 8) + c8] = cvt8v(a, b);
  }
  for (int i = gid; i < 1441792; i += gs) {  // down 2048x5632
    f32x4 a = __builtin_nontemporal_load(&((const f32x4*)dw)[2 * i]);
    f32x4 b = __builtin_nontemporal_load(&((const f32x4*)dw)[2 * i + 1]);
    ((us8*)dwB)[i] = cvt8v(a, b);
  }
}

// ---------------------------------------------------------------------------
extern "C" void kernel_launch(void* const* d_in, const int* in_sizes, int n_in,
                              void* d_out, int out_size, void* d_ws, size_t ws_size,
                              hipStream_t stream) {
  (void)in_sizes; (void)n_in; (void)out_size; (void)ws_size;
  const float* hidden = (const float*)d_in[0];
  const float* q_w  = (const float*)d_in[1];
  const float* k_w  = (const float*)d_in[2];
  const float* v_w  = (const float*)d_in[3];
  const float* o_w  = (const float*)d_in[4];
  const float* a_nw = (const float*)d_in[5];
  const float* m_nw = (const float*)d_in[6];
  const float* g_w  = (const float*)d_in[7];
  const float* u_w  = (const float*)d_in[8];
  const float* dn_w = (const float*)d_in[9];
  float* out = (float*)d_out;

  char* p = (char*)d_ws;
  size_t off = 0;
  auto take = [&](size_t bytes) -> char* {
    char* r = p + off;
    off += (bytes + 255) & ~(size_t)255;
    return r;
  };
  float* ctf          = (float*)take((size_t)1024 * 2048 * 4);
  unsigned short* ctb = (unsigned short*)take((size_t)1024 * 2048 * 2);
  unsigned short* xb  = (unsigned short*)take((size_t)1024 * 2048 * 2);
  unsigned short* hb  = (unsigned short*)take((size_t)2048 * 2048 * 2);
  unsigned short* qwB = (unsigned short*)take((size_t)2048 * 2048 * 2);
  unsigned short* kwB = (unsigned short*)take((size_t)512 * 2048 * 2);
  unsigned short* vwB = (unsigned short*)take((size_t)512 * 2048 * 2);
  unsigned short* owB = (unsigned short*)take((size_t)2048 * 2048 * 2);
  unsigned short* guB = (unsigned short*)take((size_t)11264 * 2048 * 2);
  unsigned short* dwB = (unsigned short*)take((size_t)2048 * 5632 * 2);
  unsigned short* kB  = (unsigned short*)take((size_t)3072 * 512 * 2);
  unsigned short* vtB = (unsigned short*)take((size_t)512 * 3072 * 2);
  unsigned short* oB  = (unsigned short*)take((size_t)1024 * 2048 * 2);
  unsigned short* gtB = (unsigned short*)take((size_t)1024 * 5632 * 2);
  float* Pd           = (float*)take((size_t)2 * 1024 * 2048 * 4);  // split-K partials

  unsigned short* Op = xb;            // attn partials alias xb+hb (dead there)
  float* Ml = (float*)((char*)xb + (size_t)2 * 1024 * 2048 * 2);
  float* PKV = (float*)hb;            // KV split partials alias hb (dead in-loop)

  dim3 blk(256);
  cvt_all<<<dim3(4096), blk, 0, stream>>>(hidden, q_w, k_w, v_w, o_w, g_w, u_w, dn_w,
                                          hb, qwB, kwB, vwB, owB, guB, dwB, ctf, ctb);

  gemm_dual<0><<<dim3(8, 32), blk, 0, stream>>>(hb, kwB, vwB, 2048, kB, vtB, nullptr, 512, 3072);

  for (int it = 0; it < 2; it++) {
    if (it == 0)
      rmsnorm_k<<<dim3(1024), blk, 0, stream>>>(ctf, a_nw, xb);
    else
      rmsnorm_add2_k<<<dim3(1024), blk, 0, stream>>>(Pd, xb, ctf, ctb, a_nw);
    gemm_split<<<dim3(16, 16, 2), blk, 0, stream>>>(xb, qwB, 2048, Pd, 2048);
    gemm_dual<1><<<dim3(8, 16, 2), blk, 0, stream>>>(ctb, kwB, vwB, 2048,
                                                     nullptr, nullptr, PKV, 0, 0);
    combine_kv<<<dim3(2048), blk, 0, stream>>>(PKV, kB + (size_t)2048 * 512, vtB + 2048);
    attn_k<<<dim3(16, 32, 2), blk, 0, stream>>>(Pd, kB, vtB, Op, Ml);
    attn_combine<<<dim3(2048), blk, 0, stream>>>(Op, Ml, oB);
    gemm_split<<<dim3(16, 16, 2), blk, 0, stream>>>(oB, owB, 2048, Pd, 2048);
    rmsnorm_add_k<<<dim3(1024), blk, 0, stream>>>(ctf, Pd, m_nw, xb);
    gemm_gu<<<dim3(704), blk, 0, stream>>>(xb, guB, gtB);
    gemm_split<<<dim3(16, 16, 2), blk, 0, stream>>>(gtB, dwB, 5632, Pd, 2048);
  }
  combine2_k<<<dim3(2048), blk, 0, stream>>>(Pd, xb, out);
}